// Round 3
// baseline (1637.633 us; speedup 1.0000x reference)
//
#include <hip/hip_runtime.h>
#include <hip/hip_bf16.h>
#include <cstdint>

// ---------------------------------------------------------------------------
// ThreeLayerCNN (BranchyNet early-exit), B=4096.
// Precision: conv1/conv2/exit1/exit2 fp32 (argmax parity with numpy ref);
// big FC GEMMs (l1c1, l1c2) bf16 MFMA w/ fp32 accum (output tol 0.146).
// Workspace-adaptive: batch processed in chunks sized to fit ws_size.
// conv2 is a GEMM-over-images: lane=img (coalesced), weights via scalar pipe.
// ---------------------------------------------------------------------------

typedef __bf16 bf16_t;
typedef __bf16 bf16x8 __attribute__((ext_vector_type(8)));
typedef float  f32x4  __attribute__((ext_vector_type(4)));

#define B_IMG 4096

// ---------------------------------------------------------------------------
// conv1 (1->50, 3x3) + relu + maxpool2.  x:[nimg,1,28,28] -> h1:[nimg,8480]
// ---------------------------------------------------------------------------
__global__ __launch_bounds__(256) void conv1_pool(
    const float* __restrict__ x, const float* __restrict__ w1,
    const float* __restrict__ b1, float* __restrict__ h1, int nimg)
{
    __shared__ float ws[450];
    __shared__ float bs[50];
    const int t = threadIdx.x;
    for (int i = t; i < 450; i += 256) ws[i] = w1[i];
    if (t < 50) bs[t] = b1[t];
    __syncthreads();

    const int idx = blockIdx.x * 256 + t;
    if (idx >= nimg * 169) return;
    const int b   = idx / 169;
    const int pos = idx % 169;
    const int py = pos / 13, px = pos % 13;

    const float* xp = x + (size_t)b * 784 + (2 * py) * 28 + 2 * px;
    float p[4][4];
#pragma unroll
    for (int r = 0; r < 4; ++r)
#pragma unroll
        for (int c = 0; c < 4; ++c) p[r][c] = xp[r * 28 + c];

    float* hb = h1 + (size_t)b * 8480 + pos;
    if (pos < 30) h1[(size_t)b * 8480 + 8450 + pos] = 0.f;   // zero pad cols

    for (int oc = 0; oc < 50; ++oc) {
        const float* wp = &ws[oc * 9];
        const float w00 = wp[0], w01 = wp[1], w02 = wp[2];
        const float w10 = wp[3], w11 = wp[4], w12 = wp[5];
        const float w20 = wp[6], w21 = wp[7], w22 = wp[8];
        float a[2][2];
#pragma unroll
        for (int dy = 0; dy < 2; ++dy)
#pragma unroll
            for (int dx = 0; dx < 2; ++dx) {
                a[dy][dx] = p[dy + 0][dx + 0] * w00 + p[dy + 0][dx + 1] * w01 + p[dy + 0][dx + 2] * w02
                          + p[dy + 1][dx + 0] * w10 + p[dy + 1][dx + 1] * w11 + p[dy + 1][dx + 2] * w12
                          + p[dy + 2][dx + 0] * w20 + p[dy + 2][dx + 1] * w21 + p[dy + 2][dx + 2] * w22;
            }
        float v = fmaxf(fmaxf(a[0][0], a[0][1]), fmaxf(a[1][0], a[1][1])) + bs[oc];
        hb[oc * 169] = fmaxf(v, 0.f);
    }
}

// ---------------------------------------------------------------------------
// h1 [C][8480] -> h1T [8450][C].  LDS 64x65 tiles, coalesced both sides.
// ---------------------------------------------------------------------------
__global__ __launch_bounds__(256) void transpose_h1(
    const float* __restrict__ h1, float* __restrict__ h1T, int C)
{
    __shared__ float tile[64][65];
    const int k0  = blockIdx.x * 64;
    const int im0 = blockIdx.y * 64;
    const int tx = threadIdx.x & 63;
    const int ty = threadIdx.x >> 6;    // 0..3

#pragma unroll
    for (int j = 0; j < 16; ++j) {
        const int r = ty * 16 + j;                // img offset 0..63
        const int k = k0 + tx;
        tile[r][tx] = (k < 8450) ? h1[(size_t)(im0 + r) * 8480 + k] : 0.f;
    }
    __syncthreads();
#pragma unroll
    for (int j = 0; j < 16; ++j) {
        const int kk = ty * 16 + j;               // k offset 0..63
        const int k = k0 + kk;
        if (k < 8450) h1T[(size_t)k * C + im0 + tx] = tile[tx][kk];
    }
}

// ---------------------------------------------------------------------------
// conv2 as GEMM-over-images. h1T:[8450][C] -> h2:[C][1280] (pads zeroed).
// Grid (25 pooled pos, C/64). lane=img (coalesced loads), warp=13-oc group,
// weights wave-uniform -> scalar loads. 36 FMA per (ic,oc), same tap order
// as before (exit2 argmax parity).
// ---------------------------------------------------------------------------
__global__ __launch_bounds__(256) void conv2_gemm(
    const float* __restrict__ h1T, const float* __restrict__ w2,
    const float* __restrict__ b2, float* __restrict__ h2, int C)
{
    const int p   = blockIdx.x;            // pooled pos 0..24
    const int py  = p / 5, px = p % 5;
    const int im0 = blockIdx.y * 64;
    const int lane = threadIdx.x & 63;
    const int wrp  = threadIdx.x >> 6;
    const int img  = im0 + lane;
    const int oc0 = __builtin_amdgcn_readfirstlane(wrp * 13);

    if (p == 0) {   // zero h2 pad cols for this img tile
        for (int i = threadIdx.x; i < 64 * 30; i += 256)
            h2[(size_t)(im0 + i / 30) * 1280 + 1250 + (i % 30)] = 0.f;
    }

    float acc[13][4];
#pragma unroll
    for (int j = 0; j < 13; ++j)
#pragma unroll
        for (int q = 0; q < 4; ++q) acc[j][q] = 0.f;

    const float* base = h1T + (size_t)((2 * py) * 13 + 2 * px) * C + img;

    for (int ic = 0; ic < 50; ++ic) {
        float pch[4][4];
        const float* bp = base + (size_t)ic * 169 * C;
#pragma unroll
        for (int r = 0; r < 4; ++r)
#pragma unroll
            for (int c = 0; c < 4; ++c)
                pch[r][c] = bp[(size_t)(r * 13 + c) * C];

#pragma unroll
        for (int j = 0; j < 13; ++j) {
            if (oc0 + j < 50) {
                const float* wp = w2 + ((size_t)(oc0 + j) * 50 + ic) * 9;
                const float w00 = wp[0], w01 = wp[1], w02 = wp[2];
                const float w10 = wp[3], w11 = wp[4], w12 = wp[5];
                const float w20 = wp[6], w21 = wp[7], w22 = wp[8];
#pragma unroll
                for (int dy = 0; dy < 2; ++dy)
#pragma unroll
                    for (int dx = 0; dx < 2; ++dx) {
                        acc[j][dy * 2 + dx] +=
                              pch[dy + 0][dx + 0] * w00 + pch[dy + 0][dx + 1] * w01 + pch[dy + 0][dx + 2] * w02
                            + pch[dy + 1][dx + 0] * w10 + pch[dy + 1][dx + 1] * w11 + pch[dy + 1][dx + 2] * w12
                            + pch[dy + 2][dx + 0] * w20 + pch[dy + 2][dx + 1] * w21 + pch[dy + 2][dx + 2] * w22;
                    }
            }
        }
    }

#pragma unroll
    for (int j = 0; j < 13; ++j) {
        if (oc0 + j < 50) {
            float v = fmaxf(fmaxf(acc[j][0], acc[j][1]), fmaxf(acc[j][2], acc[j][3]));
            v = fmaxf(v + b2[oc0 + j], 0.f);
            h2[(size_t)img * 1280 + (oc0 + j) * 25 + p] = v;
        }
    }
}

// ---------------------------------------------------------------------------
// conv3 (50->50 on 5x5) + relu + pool -> f3:[nimg,50]. 4 images per block.
// ---------------------------------------------------------------------------
__global__ __launch_bounds__(256) void conv3_pool(
    const float* __restrict__ h2, const float* __restrict__ w3,
    const float* __restrict__ b3, float* __restrict__ f3)
{
    __shared__ float in[5000];
    const int blk = blockIdx.x;
    const int t = threadIdx.x;
    for (int i = t; i < 5000; i += 256) {
        const int img = i / 1250, off = i % 1250;
        in[i] = h2[(size_t)(blk * 4 + img) * 1280 + off];
    }
    __syncthreads();
    const int il = t >> 6;
    const int oc = t & 63;
    if (oc >= 50) return;

    const float* ip0 = &in[il * 1250];
    float a00 = 0.f, a01 = 0.f, a10 = 0.f, a11 = 0.f;
    for (int ic = 0; ic < 50; ++ic) {
        float p[4][4];
        const float* ip = ip0 + ic * 25;
#pragma unroll
        for (int r = 0; r < 4; ++r)
#pragma unroll
            for (int c = 0; c < 4; ++c) p[r][c] = ip[r * 5 + c];
        const float* wp = &w3[((size_t)oc * 50 + ic) * 9];
        const float w00 = wp[0], w01 = wp[1], w02 = wp[2];
        const float w10 = wp[3], w11 = wp[4], w12 = wp[5];
        const float w20 = wp[6], w21 = wp[7], w22 = wp[8];
        a00 += p[0][0]*w00 + p[0][1]*w01 + p[0][2]*w02 + p[1][0]*w10 + p[1][1]*w11 + p[1][2]*w12 + p[2][0]*w20 + p[2][1]*w21 + p[2][2]*w22;
        a01 += p[0][1]*w00 + p[0][2]*w01 + p[0][3]*w02 + p[1][1]*w10 + p[1][2]*w11 + p[1][3]*w12 + p[2][1]*w20 + p[2][2]*w21 + p[2][3]*w22;
        a10 += p[1][0]*w00 + p[1][1]*w01 + p[1][2]*w02 + p[2][0]*w10 + p[2][1]*w11 + p[2][2]*w12 + p[3][0]*w20 + p[3][1]*w21 + p[3][2]*w22;
        a11 += p[1][1]*w00 + p[1][2]*w01 + p[1][3]*w02 + p[2][1]*w10 + p[2][2]*w11 + p[2][3]*w12 + p[3][1]*w20 + p[3][2]*w21 + p[3][3]*w22;
    }
    float v = fmaxf(fmaxf(a00, a01), fmaxf(a10, a11)) + b3[oc];
    f3[(size_t)(blk * 4 + il) * 50 + oc] = fmaxf(v, 0.f);
}

// ---------------------------------------------------------------------------
// exit: z = f @ dw^T + db (2 outputs); e[b] = (z0 >= z1). fp32, block/sample.
// ---------------------------------------------------------------------------
__global__ __launch_bounds__(256) void exit_kernel(
    const float* __restrict__ F, int ldf, int K,
    const float* __restrict__ dw, const float* __restrict__ db, int* __restrict__ e)
{
    const int b = blockIdx.x;
    const int t = threadIdx.x;
    const float* f = F + (size_t)b * ldf;
    float s0 = 0.f, s1 = 0.f;
    for (int i = t; i < K; i += 256) {
        const float v = f[i];
        s0 += v * dw[i];
        s1 += v * dw[K + i];
    }
    __shared__ float r0[256];
    __shared__ float r1[256];
    r0[t] = s0; r1[t] = s1;
    __syncthreads();
    for (int s = 128; s > 0; s >>= 1) {
        if (t < s) { r0[t] += r0[t + s]; r1[t] += r1[t + s]; }
        __syncthreads();
    }
    if (t == 0) e[b] = (r0[0] + db[0] >= r1[0] + db[1]) ? 1 : 0;
}

// ---------------------------------------------------------------------------
// fp32 [N,K] -> bf16 [Np,Kp], zero-padded.
// ---------------------------------------------------------------------------
__global__ __launch_bounds__(256) void w_to_bf16(
    const float* __restrict__ src, bf16_t* __restrict__ dst, int N, int K, int Kp, int total)
{
    const int idx = blockIdx.x * 256 + threadIdx.x;
    if (idx >= total) return;
    const int n = idx / Kp, k = idx % Kp;
    const float v = (n < N && k < K) ? src[(size_t)n * K + k] : 0.f;
    dst[idx] = (bf16_t)v;
}

// ---------------------------------------------------------------------------
// MFMA GEMM: C[M,ldc] = bf16(A_f32[M,lda]) @ W_bf16[Np,Kp]^T + bias
// BM=128, BN=64, BK=32. LDS row stride 40.
// ---------------------------------------------------------------------------
__global__ __launch_bounds__(256) void gemm_f32a_bf16w(
    const float* __restrict__ A, int lda,
    const bf16_t* __restrict__ W,
    const float* __restrict__ bias, float* __restrict__ C,
    int Kp, int Nout, int ldc)
{
    __shared__ __align__(16) bf16_t As[128 * 40];
    __shared__ __align__(16) bf16_t Bs[64 * 40];

    const int t = threadIdx.x;
    const int m0 = blockIdx.x * 128;
    const int n0 = blockIdx.y * 64;
    const int wave = t >> 6;
    const int lane = t & 63;
    const int wm = (wave >> 1) * 64;
    const int wn = (wave & 1) * 32;
    const int quad = lane >> 4;
    const int lr = lane & 15;

    f32x4 acc[4][2];
#pragma unroll
    for (int i = 0; i < 4; ++i)
#pragma unroll
        for (int j = 0; j < 2; ++j) acc[i][j] = (f32x4)0.f;

    const int ar = t >> 2;          // 0..63
    const int ac = (t & 3) * 8;     // 0,8,16,24

    for (int k0 = 0; k0 < Kp; k0 += 32) {
        __syncthreads();
#pragma unroll
        for (int h = 0; h < 2; ++h) {
            const float* ap = A + (size_t)(m0 + ar + h * 64) * lda + k0 + ac;
            const float4 f0 = *(const float4*)ap;
            const float4 f1 = *(const float4*)(ap + 4);
            bf16x8 v;
            v[0] = (bf16_t)f0.x; v[1] = (bf16_t)f0.y; v[2] = (bf16_t)f0.z; v[3] = (bf16_t)f0.w;
            v[4] = (bf16_t)f1.x; v[5] = (bf16_t)f1.y; v[6] = (bf16_t)f1.z; v[7] = (bf16_t)f1.w;
            *(bf16x8*)&As[(ar + h * 64) * 40 + ac] = v;
        }
        *(uint4*)&Bs[ar * 40 + ac] = *(const uint4*)&W[(size_t)(n0 + ar) * Kp + k0 + ac];
        __syncthreads();

        bf16x8 af[4], bfr[2];
#pragma unroll
        for (int i = 0; i < 4; ++i)
            af[i] = *(const bf16x8*)&As[(wm + i * 16 + lr) * 40 + quad * 8];
#pragma unroll
        for (int j = 0; j < 2; ++j)
            bfr[j] = *(const bf16x8*)&Bs[(wn + j * 16 + lr) * 40 + quad * 8];
#pragma unroll
        for (int i = 0; i < 4; ++i)
#pragma unroll
            for (int j = 0; j < 2; ++j)
                acc[i][j] = __builtin_amdgcn_mfma_f32_16x16x32_bf16(af[i], bfr[j], acc[i][j], 0, 0, 0);
    }

#pragma unroll
    for (int j = 0; j < 2; ++j) {
        const int n = n0 + wn + j * 16 + lr;
        const float bv = (n < Nout) ? bias[n] : 0.f;
#pragma unroll
        for (int i = 0; i < 4; ++i) {
            const int mrow = m0 + wm + i * 16 + quad * 4;
#pragma unroll
            for (int r = 0; r < 4; ++r)
                C[(size_t)(mrow + r) * ldc + n] = acc[i][j][r] + bv;
        }
    }
}

// ---------------------------------------------------------------------------
// out[b,o<10] = U[b,:K] @ W[o,:K] + bias[o]
// ---------------------------------------------------------------------------
__global__ __launch_bounds__(256) void lin10(
    const float* __restrict__ U, int ldu, int K,
    const float* __restrict__ W, const float* __restrict__ bias,
    float* __restrict__ out, int nb)
{
    const int idx = blockIdx.x * 256 + threadIdx.x;
    const int b = idx >> 4, o = idx & 15;
    if (o >= 10 || b >= nb) return;
    const float* u = U + (size_t)b * ldu;
    const float* w = W + (size_t)o * K;
    float s = 0.f;
    for (int k = 0; k < K; ++k) s += u[k] * w[k];
    out[(size_t)b * 10 + o] = s + bias[o];
}

// ---------------------------------------------------------------------------
// u3[b,o<500] = relu(f3[b,:50] @ l1w[o,:50] + l1b[o]); u3 row stride 512.
// ---------------------------------------------------------------------------
__global__ __launch_bounds__(256) void lin500(
    const float* __restrict__ f3, const float* __restrict__ w,
    const float* __restrict__ bias, float* __restrict__ u3)
{
    __shared__ float fs[50];
    const int b = blockIdx.x;
    const int t = threadIdx.x;
    if (t < 50) fs[t] = f3[(size_t)b * 50 + t];
    __syncthreads();
    for (int o = t; o < 500; o += 256) {
        float s = 0.f;
#pragma unroll
        for (int k = 0; k < 50; ++k) s += fs[k] * w[o * 50 + k];
        u3[(size_t)b * 512 + o] = fmaxf(s + bias[o], 0.f);
    }
}

// ---------------------------------------------------------------------------
// select per exits, log_softmax over 10, write final output (full batch).
// ---------------------------------------------------------------------------
__global__ __launch_bounds__(256) void final_select(
    const int* __restrict__ e1, const int* __restrict__ e2,
    const float* __restrict__ o1, const float* __restrict__ o2,
    const float* __restrict__ o3, float* __restrict__ out)
{
    const int b = blockIdx.x * 256 + threadIdx.x;
    if (b >= B_IMG) return;
    const float* src = e1[b] ? o1 : (e2[b] ? o2 : o3);
    src += (size_t)b * 10;
    float v[10];
    float m = -3.4e38f;
#pragma unroll
    for (int o = 0; o < 10; ++o) { v[o] = src[o]; m = fmaxf(m, v[o]); }
    float s = 0.f;
#pragma unroll
    for (int o = 0; o < 10; ++o) s += expf(v[o] - m);
    const float ls = logf(s);
#pragma unroll
    for (int o = 0; o < 10; ++o) out[(size_t)b * 10 + o] = v[o] - m - ls;
}

// ---------------------------------------------------------------------------
static inline size_t align256(size_t v) { return (v + 255) & ~(size_t)255; }

extern "C" void kernel_launch(void* const* d_in, const int* in_sizes, int n_in,
                              void* d_out, int out_size, void* d_ws, size_t ws_size,
                              hipStream_t stream)
{
    const float* x     = (const float*)d_in[0];
    const float* c1w   = (const float*)d_in[1];
    const float* c1b   = (const float*)d_in[2];
    const float* c2w   = (const float*)d_in[3];
    const float* c2b   = (const float*)d_in[4];
    const float* c3w   = (const float*)d_in[5];
    const float* c3b   = (const float*)d_in[6];
    const float* l1c1w = (const float*)d_in[7];
    const float* l1c1b = (const float*)d_in[8];
    const float* l2c1w = (const float*)d_in[9];
    const float* l2c1b = (const float*)d_in[10];
    const float* l1c2w = (const float*)d_in[11];
    const float* l1c2b = (const float*)d_in[12];
    const float* l2c2w = (const float*)d_in[13];
    const float* l2c2b = (const float*)d_in[14];
    const float* l1w   = (const float*)d_in[15];
    const float* l1b   = (const float*)d_in[16];
    const float* l2w   = (const float*)d_in[17];
    const float* l2b   = (const float*)d_in[18];
    const float* d1w   = (const float*)d_in[19];
    const float* d1b   = (const float*)d_in[20];
    const float* d2w   = (const float*)d_in[21];
    const float* d2b   = (const float*)d_in[22];

    // ---- persistent layout (full batch) ----
    size_t off = 0;
    const size_t oWb1  = off; off = align256(off + (size_t)512 * 8480 * 2);
    const size_t oWb2  = off; off = align256(off + (size_t)512 * 1280 * 2);
    const size_t oOut1 = off; off = align256(off + (size_t)B_IMG * 10 * 4);
    const size_t oOut2 = off; off = align256(off + (size_t)B_IMG * 10 * 4);
    const size_t oOut3 = off; off = align256(off + (size_t)B_IMG * 10 * 4);
    const size_t oE1   = off; off = align256(off + (size_t)B_IMG * 4);
    const size_t oE2   = off; off = align256(off + (size_t)B_IMG * 4);
    const size_t persist = off;

    // ---- per-chunk bytes: h1 + h1T + h2 + u1 + u2 + u3 + f3 ----
    auto chunk_bytes = [](int C) {
        size_t s = 0;
        s += align256((size_t)C * 8480 * 4);   // h1
        s += align256((size_t)8450 * C * 4);   // h1T
        s += align256((size_t)C * 1280 * 4);   // h2
        s += align256((size_t)C * 512 * 4);    // u1
        s += align256((size_t)C * 512 * 4);    // u2
        s += align256((size_t)C * 512 * 4);    // u3
        s += align256((size_t)C * 50 * 4);     // f3
        return s;
    };
    int C = B_IMG;
    while (C > 256 && persist + chunk_bytes(C) > ws_size) C >>= 1;

    char* ws = (char*)d_ws;
    bf16_t* Wb1  = (bf16_t*)(ws + oWb1);
    bf16_t* Wb2  = (bf16_t*)(ws + oWb2);
    float*  out1 = (float*) (ws + oOut1);
    float*  out2 = (float*) (ws + oOut2);
    float*  out3 = (float*) (ws + oOut3);
    int*    e1   = (int*)   (ws + oE1);
    int*    e2   = (int*)   (ws + oE2);

    size_t co = persist;
    float* h1  = (float*)(ws + co); co += align256((size_t)C * 8480 * 4);
    float* h1T = (float*)(ws + co); co += align256((size_t)8450 * C * 4);
    float* h2  = (float*)(ws + co); co += align256((size_t)C * 1280 * 4);
    float* u1  = (float*)(ws + co); co += align256((size_t)C * 512 * 4);
    float* u2  = (float*)(ws + co); co += align256((size_t)C * 512 * 4);
    float* u3  = (float*)(ws + co); co += align256((size_t)C * 512 * 4);
    float* f3  = (float*)(ws + co); co += align256((size_t)C * 50 * 4);

    float* out = (float*)d_out;

    // weight conversion (once)
    w_to_bf16<<<(512 * 8480) / 256, 256, 0, stream>>>(l1c1w, Wb1, 500, 8450, 8480, 512 * 8480);
    w_to_bf16<<<(512 * 1280) / 256, 256, 0, stream>>>(l1c2w, Wb2, 500, 1250, 1280, 512 * 1280);

    for (int b0 = 0; b0 < B_IMG; b0 += C) {
        // stage 1
        conv1_pool<<<(C * 169 + 255) / 256, 256, 0, stream>>>(x + (size_t)b0 * 784, c1w, c1b, h1, C);
        exit_kernel<<<C, 256, 0, stream>>>(h1, 8480, 8450, d1w, d1b, e1 + b0);
        gemm_f32a_bf16w<<<dim3(C / 128, 8), 256, 0, stream>>>(h1, 8480, Wb1, l1c1b, u1, 8480, 500, 512);
        lin10<<<(C * 16 + 255) / 256, 256, 0, stream>>>(u1, 512, 500, l2c1w, l2c1b, out1 + (size_t)b0 * 10, C);

        // stage 2
        transpose_h1<<<dim3(133, C / 64), 256, 0, stream>>>(h1, h1T, C);
        conv2_gemm<<<dim3(25, C / 64), 256, 0, stream>>>(h1T, c2w, c2b, h2, C);
        exit_kernel<<<C, 256, 0, stream>>>(h2, 1280, 1250, d2w, d2b, e2 + b0);
        gemm_f32a_bf16w<<<dim3(C / 128, 8), 256, 0, stream>>>(h2, 1280, Wb2, l1c2b, u2, 1280, 500, 512);
        lin10<<<(C * 16 + 255) / 256, 256, 0, stream>>>(u2, 512, 500, l2c2w, l2c2b, out2 + (size_t)b0 * 10, C);

        // stage 3
        conv3_pool<<<C / 4, 256, 0, stream>>>(h2, c3w, c3b, f3);
        lin500<<<C, 256, 0, stream>>>(f3, l1w, l1b, u3);
        lin10<<<(C * 16 + 255) / 256, 256, 0, stream>>>(u3, 512, 500, l2w, l2b, out3 + (size_t)b0 * 10, C);
    }

    final_select<<<B_IMG / 256, 256, 0, stream>>>(e1, e2, out1, out2, out3, out);

    (void)in_sizes; (void)n_in; (void)out_size; (void)ws_size;
}

// Round 4
// 933.832 us; speedup vs baseline: 1.7537x; 1.7537x over previous
//
#include <hip/hip_runtime.h>
#include <hip/hip_bf16.h>
#include <cstdint>

// ---------------------------------------------------------------------------
// ThreeLayerCNN (BranchyNet early-exit), B=4096.
// Precision: conv1/conv2/exit1/exit2 fp32 (argmax parity with numpy ref);
// big FC GEMMs (l1c1, l1c2) bf16 MFMA w/ fp32 accum (output tol 0.146).
// Round 4: round-2 structure (C=4096 fits, ~181 MB) with
//   - conv2_pool: weights double-buffered in LDS (kills per-lane VMEM loads)
//   - lin10: 16-img x 16-kstrip blocks, coalesced, LDS reduce
//   - single shared u buffer
// ---------------------------------------------------------------------------

typedef __bf16 bf16_t;
typedef __bf16 bf16x8 __attribute__((ext_vector_type(8)));
typedef float  f32x4  __attribute__((ext_vector_type(4)));

#define B_IMG 4096

// ---------------------------------------------------------------------------
// conv1 (1->50, 3x3) + relu + maxpool2.  x:[nimg,1,28,28] -> h1:[nimg,8480]
// ---------------------------------------------------------------------------
__global__ __launch_bounds__(256) void conv1_pool(
    const float* __restrict__ x, const float* __restrict__ w1,
    const float* __restrict__ b1, float* __restrict__ h1, int nimg)
{
    __shared__ float ws[450];
    __shared__ float bs[50];
    const int t = threadIdx.x;
    for (int i = t; i < 450; i += 256) ws[i] = w1[i];
    if (t < 50) bs[t] = b1[t];
    __syncthreads();

    const int idx = blockIdx.x * 256 + t;
    if (idx >= nimg * 169) return;
    const int b   = idx / 169;
    const int pos = idx % 169;
    const int py = pos / 13, px = pos % 13;

    const float* xp = x + (size_t)b * 784 + (2 * py) * 28 + 2 * px;
    float p[4][4];
#pragma unroll
    for (int r = 0; r < 4; ++r)
#pragma unroll
        for (int c = 0; c < 4; ++c) p[r][c] = xp[r * 28 + c];

    float* hb = h1 + (size_t)b * 8480 + pos;
    if (pos < 30) h1[(size_t)b * 8480 + 8450 + pos] = 0.f;   // zero pad cols

    for (int oc = 0; oc < 50; ++oc) {
        const float* wp = &ws[oc * 9];
        const float w00 = wp[0], w01 = wp[1], w02 = wp[2];
        const float w10 = wp[3], w11 = wp[4], w12 = wp[5];
        const float w20 = wp[6], w21 = wp[7], w22 = wp[8];
        float a[2][2];
#pragma unroll
        for (int dy = 0; dy < 2; ++dy)
#pragma unroll
            for (int dx = 0; dx < 2; ++dx) {
                a[dy][dx] = p[dy + 0][dx + 0] * w00 + p[dy + 0][dx + 1] * w01 + p[dy + 0][dx + 2] * w02
                          + p[dy + 1][dx + 0] * w10 + p[dy + 1][dx + 1] * w11 + p[dy + 1][dx + 2] * w12
                          + p[dy + 2][dx + 0] * w20 + p[dy + 2][dx + 1] * w21 + p[dy + 2][dx + 2] * w22;
            }
        float v = fmaxf(fmaxf(a[0][0], a[0][1]), fmaxf(a[1][0], a[1][1])) + bs[oc];
        hb[oc * 169] = fmaxf(v, 0.f);
    }
}

// ---------------------------------------------------------------------------
// conv2 (50->50) + relu + pool. h1:[nimg,8480] -> h2:[nimg,1280] (pads zeroed)
// Block per image; input (33.8KB) + double-buffered weights (19.2KB) in LDS.
// Thread: 5 oc x 1 pos. FP order identical to round 2 (exit2 argmax parity).
// ---------------------------------------------------------------------------
__global__ __launch_bounds__(256) void conv2_pool(
    const float* __restrict__ h1, const float* __restrict__ w2,
    const float* __restrict__ b2, float* __restrict__ h2)
{
    __shared__ float in[8450];
    __shared__ float wbuf[2][2400];   // [buf][icl*600 + oc*12 + j], j<9
    const int b = blockIdx.x;
    const int t = threadIdx.x;
    for (int i = t; i < 8450; i += 256) in[i] = h1[(size_t)b * 8480 + i];
    for (int s = t; s < 1800; s += 256) {
        const int oc = s / 36, r = s - oc * 36, icl = r / 9, j = r - icl * 9;
        wbuf[0][icl * 600 + oc * 12 + j] = w2[oc * 450 + icl * 9 + j];
    }
    __syncthreads();
    if (t < 30) h2[(size_t)b * 1280 + 1250 + t] = 0.f;       // zero pad cols

    const int ocg = t / 25;
    const int pos = t % 25;
    const int py = pos / 5, px = pos % 5;
    const int oc0 = ocg * 5;
    const bool act = (t < 250);

    float acc[5][4];
#pragma unroll
    for (int j = 0; j < 5; ++j)
#pragma unroll
        for (int q = 0; q < 4; ++q) acc[j][q] = 0.f;

    const float* ib = &in[(2 * py) * 13 + 2 * px];

    for (int ic0 = 0; ic0 < 50; ic0 += 4) {
        const int cur = (ic0 >> 2) & 1;
        // prefetch next 4 input channels' weights into the other buffer
        if (ic0 + 4 < 50) {
            const int nxt = cur ^ 1;
            for (int s = t; s < 1800; s += 256) {
                const int oc = s / 36, r = s - oc * 36, icl = r / 9, j = r - icl * 9;
                const int ic = ic0 + 4 + icl;
                if (ic < 50)
                    wbuf[nxt][icl * 600 + oc * 12 + j] = w2[oc * 450 + ic * 9 + j];
            }
        }
        if (act) {
            const int nic = (50 - ic0 < 4) ? (50 - ic0) : 4;
            for (int icl = 0; icl < nic; ++icl) {
                const int ic = ic0 + icl;
                float p[4][4];
                const float* ip = ib + ic * 169;
#pragma unroll
                for (int r = 0; r < 4; ++r)
#pragma unroll
                    for (int c = 0; c < 4; ++c) p[r][c] = ip[r * 13 + c];
                const float* wl = &wbuf[cur][icl * 600 + oc0 * 12];
#pragma unroll
                for (int j = 0; j < 5; ++j) {
                    const float* wp = wl + j * 12;
                    const float w00 = wp[0], w01 = wp[1], w02 = wp[2];
                    const float w10 = wp[3], w11 = wp[4], w12 = wp[5];
                    const float w20 = wp[6], w21 = wp[7], w22 = wp[8];
#pragma unroll
                    for (int dy = 0; dy < 2; ++dy)
#pragma unroll
                        for (int dx = 0; dx < 2; ++dx) {
                            acc[j][dy * 2 + dx] +=
                                  p[dy + 0][dx + 0] * w00 + p[dy + 0][dx + 1] * w01 + p[dy + 0][dx + 2] * w02
                                + p[dy + 1][dx + 0] * w10 + p[dy + 1][dx + 1] * w11 + p[dy + 1][dx + 2] * w12
                                + p[dy + 2][dx + 0] * w20 + p[dy + 2][dx + 1] * w21 + p[dy + 2][dx + 2] * w22;
                        }
                }
            }
        }
        __syncthreads();
    }

    if (act) {
#pragma unroll
        for (int j = 0; j < 5; ++j) {
            float v = fmaxf(fmaxf(acc[j][0], acc[j][1]), fmaxf(acc[j][2], acc[j][3]));
            h2[(size_t)b * 1280 + (oc0 + j) * 25 + pos] = fmaxf(v + b2[oc0 + j], 0.f);
        }
    }
}

// ---------------------------------------------------------------------------
// conv3 (50->50 on 5x5) + relu + pool -> f3:[nimg,50]. 4 images per block.
// ---------------------------------------------------------------------------
__global__ __launch_bounds__(256) void conv3_pool(
    const float* __restrict__ h2, const float* __restrict__ w3,
    const float* __restrict__ b3, float* __restrict__ f3)
{
    __shared__ float in[5000];
    const int blk = blockIdx.x;
    const int t = threadIdx.x;
    for (int i = t; i < 5000; i += 256) {
        const int img = i / 1250, off = i % 1250;
        in[i] = h2[(size_t)(blk * 4 + img) * 1280 + off];
    }
    __syncthreads();
    const int il = t >> 6;
    const int oc = t & 63;
    if (oc >= 50) return;

    const float* ip0 = &in[il * 1250];
    float a00 = 0.f, a01 = 0.f, a10 = 0.f, a11 = 0.f;
    for (int ic = 0; ic < 50; ++ic) {
        float p[4][4];
        const float* ip = ip0 + ic * 25;
#pragma unroll
        for (int r = 0; r < 4; ++r)
#pragma unroll
            for (int c = 0; c < 4; ++c) p[r][c] = ip[r * 5 + c];
        const float* wp = &w3[((size_t)oc * 50 + ic) * 9];
        const float w00 = wp[0], w01 = wp[1], w02 = wp[2];
        const float w10 = wp[3], w11 = wp[4], w12 = wp[5];
        const float w20 = wp[6], w21 = wp[7], w22 = wp[8];
        a00 += p[0][0]*w00 + p[0][1]*w01 + p[0][2]*w02 + p[1][0]*w10 + p[1][1]*w11 + p[1][2]*w12 + p[2][0]*w20 + p[2][1]*w21 + p[2][2]*w22;
        a01 += p[0][1]*w00 + p[0][2]*w01 + p[0][3]*w02 + p[1][1]*w10 + p[1][2]*w11 + p[1][3]*w12 + p[2][1]*w20 + p[2][2]*w21 + p[2][3]*w22;
        a10 += p[1][0]*w00 + p[1][1]*w01 + p[1][2]*w02 + p[2][0]*w10 + p[2][1]*w11 + p[2][2]*w12 + p[3][0]*w20 + p[3][1]*w21 + p[3][2]*w22;
        a11 += p[1][1]*w00 + p[1][2]*w01 + p[1][3]*w02 + p[2][1]*w10 + p[2][2]*w11 + p[2][3]*w12 + p[3][1]*w20 + p[3][2]*w21 + p[3][3]*w22;
    }
    float v = fmaxf(fmaxf(a00, a01), fmaxf(a10, a11)) + b3[oc];
    f3[(size_t)(blk * 4 + il) * 50 + oc] = fmaxf(v, 0.f);
}

// ---------------------------------------------------------------------------
// exit: z = f @ dw^T + db (2 outputs); e[b] = (z0 >= z1). fp32, block/sample.
// ---------------------------------------------------------------------------
__global__ __launch_bounds__(256) void exit_kernel(
    const float* __restrict__ F, int ldf, int K,
    const float* __restrict__ dw, const float* __restrict__ db, int* __restrict__ e)
{
    const int b = blockIdx.x;
    const int t = threadIdx.x;
    const float* f = F + (size_t)b * ldf;
    float s0 = 0.f, s1 = 0.f;
    for (int i = t; i < K; i += 256) {
        const float v = f[i];
        s0 += v * dw[i];
        s1 += v * dw[K + i];
    }
    __shared__ float r0[256];
    __shared__ float r1[256];
    r0[t] = s0; r1[t] = s1;
    __syncthreads();
    for (int s = 128; s > 0; s >>= 1) {
        if (t < s) { r0[t] += r0[t + s]; r1[t] += r1[t + s]; }
        __syncthreads();
    }
    if (t == 0) e[b] = (r0[0] + db[0] >= r1[0] + db[1]) ? 1 : 0;
}

// ---------------------------------------------------------------------------
// fp32 [N,K] -> bf16 [Np,Kp], zero-padded.
// ---------------------------------------------------------------------------
__global__ __launch_bounds__(256) void w_to_bf16(
    const float* __restrict__ src, bf16_t* __restrict__ dst, int N, int K, int Kp, int total)
{
    const int idx = blockIdx.x * 256 + threadIdx.x;
    if (idx >= total) return;
    const int n = idx / Kp, k = idx % Kp;
    const float v = (n < N && k < K) ? src[(size_t)n * K + k] : 0.f;
    dst[idx] = (bf16_t)v;
}

// ---------------------------------------------------------------------------
// MFMA GEMM: C[M,ldc] = bf16(A_f32[M,lda]) @ W_bf16[Np,Kp]^T + bias
// BM=128, BN=64, BK=32. LDS row stride 40.
// ---------------------------------------------------------------------------
__global__ __launch_bounds__(256) void gemm_f32a_bf16w(
    const float* __restrict__ A, int lda,
    const bf16_t* __restrict__ W,
    const float* __restrict__ bias, float* __restrict__ C,
    int Kp, int Nout, int ldc)
{
    __shared__ __align__(16) bf16_t As[128 * 40];
    __shared__ __align__(16) bf16_t Bs[64 * 40];

    const int t = threadIdx.x;
    const int m0 = blockIdx.x * 128;
    const int n0 = blockIdx.y * 64;
    const int wave = t >> 6;
    const int lane = t & 63;
    const int wm = (wave >> 1) * 64;
    const int wn = (wave & 1) * 32;
    const int quad = lane >> 4;
    const int lr = lane & 15;

    f32x4 acc[4][2];
#pragma unroll
    for (int i = 0; i < 4; ++i)
#pragma unroll
        for (int j = 0; j < 2; ++j) acc[i][j] = (f32x4)0.f;

    const int ar = t >> 2;          // 0..63
    const int ac = (t & 3) * 8;     // 0,8,16,24

    for (int k0 = 0; k0 < Kp; k0 += 32) {
        __syncthreads();
#pragma unroll
        for (int h = 0; h < 2; ++h) {
            const float* ap = A + (size_t)(m0 + ar + h * 64) * lda + k0 + ac;
            const float4 f0 = *(const float4*)ap;
            const float4 f1 = *(const float4*)(ap + 4);
            bf16x8 v;
            v[0] = (bf16_t)f0.x; v[1] = (bf16_t)f0.y; v[2] = (bf16_t)f0.z; v[3] = (bf16_t)f0.w;
            v[4] = (bf16_t)f1.x; v[5] = (bf16_t)f1.y; v[6] = (bf16_t)f1.z; v[7] = (bf16_t)f1.w;
            *(bf16x8*)&As[(ar + h * 64) * 40 + ac] = v;
        }
        *(uint4*)&Bs[ar * 40 + ac] = *(const uint4*)&W[(size_t)(n0 + ar) * Kp + k0 + ac];
        __syncthreads();

        bf16x8 af[4], bfr[2];
#pragma unroll
        for (int i = 0; i < 4; ++i)
            af[i] = *(const bf16x8*)&As[(wm + i * 16 + lr) * 40 + quad * 8];
#pragma unroll
        for (int j = 0; j < 2; ++j)
            bfr[j] = *(const bf16x8*)&Bs[(wn + j * 16 + lr) * 40 + quad * 8];
#pragma unroll
        for (int i = 0; i < 4; ++i)
#pragma unroll
            for (int j = 0; j < 2; ++j)
                acc[i][j] = __builtin_amdgcn_mfma_f32_16x16x32_bf16(af[i], bfr[j], acc[i][j], 0, 0, 0);
    }

#pragma unroll
    for (int j = 0; j < 2; ++j) {
        const int n = n0 + wn + j * 16 + lr;
        const float bv = (n < Nout) ? bias[n] : 0.f;
#pragma unroll
        for (int i = 0; i < 4; ++i) {
            const int mrow = m0 + wm + i * 16 + quad * 4;
#pragma unroll
            for (int r = 0; r < 4; ++r)
                C[(size_t)(mrow + r) * ldc + n] = acc[i][j][r] + bv;
        }
    }
}

// ---------------------------------------------------------------------------
// out[b,o<10] = U[b,:500] @ W[o,:500] + bias[o].
// Block: 256 thr = 16 images x 16 k-strips (lane-adjacent = k, coalesced).
// U row stride ldu=512; cols 500..511 may be garbage -> W guarded to 0.
// ---------------------------------------------------------------------------
__global__ __launch_bounds__(256) void lin10(
    const float* __restrict__ U, int ldu,
    const float* __restrict__ W, const float* __restrict__ bias,
    float* __restrict__ out)
{
    __shared__ float red[16][10][17];
    const int t = threadIdx.x;
    const int ks = t & 15;
    const int il = t >> 4;
    const int b  = blockIdx.x * 16 + il;
    const float* u = U + (size_t)b * ldu;

    float acc[10];
#pragma unroll
    for (int o = 0; o < 10; ++o) acc[o] = 0.f;

    for (int i = 0; i < 31; ++i) {
        const int k = ks + i * 16;          // <= 495
        const float uv = u[k];
#pragma unroll
        for (int o = 0; o < 10; ++o) acc[o] += uv * W[o * 500 + k];
    }
    {   // tail: k = 496..511, valid only k<500
        const int k = ks + 496;
        if (k < 500) {
            const float uv = u[k];
#pragma unroll
            for (int o = 0; o < 10; ++o) acc[o] += uv * W[o * 500 + k];
        }
    }
#pragma unroll
    for (int o = 0; o < 10; ++o) red[il][o][ks] = acc[o];
    __syncthreads();
    if (t < 160) {
        const int il2 = t / 10, o = t - il2 * 10;
        float s = 0.f;
#pragma unroll
        for (int q = 0; q < 16; ++q) s += red[il2][o][q];
        out[(size_t)(blockIdx.x * 16 + il2) * 10 + o] = s + bias[o];
    }
}

// ---------------------------------------------------------------------------
// u3[b,o<500] = relu(f3[b,:50] @ l1w[o,:50] + l1b[o]); u3 row stride 512.
// ---------------------------------------------------------------------------
__global__ __launch_bounds__(256) void lin500(
    const float* __restrict__ f3, const float* __restrict__ w,
    const float* __restrict__ bias, float* __restrict__ u3)
{
    __shared__ float fs[50];
    const int b = blockIdx.x;
    const int t = threadIdx.x;
    if (t < 50) fs[t] = f3[(size_t)b * 50 + t];
    __syncthreads();
    for (int o = t; o < 500; o += 256) {
        float s = 0.f;
#pragma unroll
        for (int k = 0; k < 50; ++k) s += fs[k] * w[o * 50 + k];
        u3[(size_t)b * 512 + o] = fmaxf(s + bias[o], 0.f);
    }
}

// ---------------------------------------------------------------------------
// select per exits, log_softmax over 10, write final output (full batch).
// ---------------------------------------------------------------------------
__global__ __launch_bounds__(256) void final_select(
    const int* __restrict__ e1, const int* __restrict__ e2,
    const float* __restrict__ o1, const float* __restrict__ o2,
    const float* __restrict__ o3, float* __restrict__ out)
{
    const int b = blockIdx.x * 256 + threadIdx.x;
    if (b >= B_IMG) return;
    const float* src = e1[b] ? o1 : (e2[b] ? o2 : o3);
    src += (size_t)b * 10;
    float v[10];
    float m = -3.4e38f;
#pragma unroll
    for (int o = 0; o < 10; ++o) { v[o] = src[o]; m = fmaxf(m, v[o]); }
    float s = 0.f;
#pragma unroll
    for (int o = 0; o < 10; ++o) s += expf(v[o] - m);
    const float ls = logf(s);
#pragma unroll
    for (int o = 0; o < 10; ++o) out[(size_t)b * 10 + o] = v[o] - m - ls;
}

// ---------------------------------------------------------------------------
static inline size_t align256(size_t v) { return (v + 255) & ~(size_t)255; }

extern "C" void kernel_launch(void* const* d_in, const int* in_sizes, int n_in,
                              void* d_out, int out_size, void* d_ws, size_t ws_size,
                              hipStream_t stream)
{
    const float* x     = (const float*)d_in[0];
    const float* c1w   = (const float*)d_in[1];
    const float* c1b   = (const float*)d_in[2];
    const float* c2w   = (const float*)d_in[3];
    const float* c2b   = (const float*)d_in[4];
    const float* c3w   = (const float*)d_in[5];
    const float* c3b   = (const float*)d_in[6];
    const float* l1c1w = (const float*)d_in[7];
    const float* l1c1b = (const float*)d_in[8];
    const float* l2c1w = (const float*)d_in[9];
    const float* l2c1b = (const float*)d_in[10];
    const float* l1c2w = (const float*)d_in[11];
    const float* l1c2b = (const float*)d_in[12];
    const float* l2c2w = (const float*)d_in[13];
    const float* l2c2b = (const float*)d_in[14];
    const float* l1w   = (const float*)d_in[15];
    const float* l1b   = (const float*)d_in[16];
    const float* l2w   = (const float*)d_in[17];
    const float* l2b   = (const float*)d_in[18];
    const float* d1w   = (const float*)d_in[19];
    const float* d1b   = (const float*)d_in[20];
    const float* d2w   = (const float*)d_in[21];
    const float* d2b   = (const float*)d_in[22];

    // ---- persistent layout (full batch) ----
    size_t off = 0;
    const size_t oWb1  = off; off = align256(off + (size_t)512 * 8480 * 2);
    const size_t oWb2  = off; off = align256(off + (size_t)512 * 1280 * 2);
    const size_t oOut1 = off; off = align256(off + (size_t)B_IMG * 10 * 4);
    const size_t oOut2 = off; off = align256(off + (size_t)B_IMG * 10 * 4);
    const size_t oOut3 = off; off = align256(off + (size_t)B_IMG * 10 * 4);
    const size_t oE1   = off; off = align256(off + (size_t)B_IMG * 4);
    const size_t oE2   = off; off = align256(off + (size_t)B_IMG * 4);
    const size_t persist = off;

    // ---- per-chunk bytes: h1 + h2 + u(shared) + f3 ----
    auto chunk_bytes = [](int C) {
        size_t s = 0;
        s += align256((size_t)C * 8480 * 4);   // h1
        s += align256((size_t)C * 1280 * 4);   // h2
        s += align256((size_t)C * 512 * 4);    // u (shared across stages)
        s += align256((size_t)C * 50 * 4);     // f3
        return s;
    };
    int C = B_IMG;
    while (C > 256 && persist + chunk_bytes(C) > ws_size) C >>= 1;

    char* ws = (char*)d_ws;
    bf16_t* Wb1  = (bf16_t*)(ws + oWb1);
    bf16_t* Wb2  = (bf16_t*)(ws + oWb2);
    float*  out1 = (float*) (ws + oOut1);
    float*  out2 = (float*) (ws + oOut2);
    float*  out3 = (float*) (ws + oOut3);
    int*    e1   = (int*)   (ws + oE1);
    int*    e2   = (int*)   (ws + oE2);

    size_t co = persist;
    float* h1 = (float*)(ws + co); co += align256((size_t)C * 8480 * 4);
    float* h2 = (float*)(ws + co); co += align256((size_t)C * 1280 * 4);
    float* u  = (float*)(ws + co); co += align256((size_t)C * 512 * 4);
    float* f3 = (float*)(ws + co); co += align256((size_t)C * 50 * 4);

    float* out = (float*)d_out;

    // weight conversion (once)
    w_to_bf16<<<(512 * 8480) / 256, 256, 0, stream>>>(l1c1w, Wb1, 500, 8450, 8480, 512 * 8480);
    w_to_bf16<<<(512 * 1280) / 256, 256, 0, stream>>>(l1c2w, Wb2, 500, 1250, 1280, 512 * 1280);

    for (int b0 = 0; b0 < B_IMG; b0 += C) {
        // stage 1
        conv1_pool<<<(C * 169 + 255) / 256, 256, 0, stream>>>(x + (size_t)b0 * 784, c1w, c1b, h1, C);
        exit_kernel<<<C, 256, 0, stream>>>(h1, 8480, 8450, d1w, d1b, e1 + b0);
        gemm_f32a_bf16w<<<dim3(C / 128, 8), 256, 0, stream>>>(h1, 8480, Wb1, l1c1b, u, 8480, 500, 512);
        lin10<<<C / 16, 256, 0, stream>>>(u, 512, l2c1w, l2c1b, out1 + (size_t)b0 * 10);

        // stage 2
        conv2_pool<<<C, 256, 0, stream>>>(h1, c2w, c2b, h2);
        exit_kernel<<<C, 256, 0, stream>>>(h2, 1280, 1250, d2w, d2b, e2 + b0);
        gemm_f32a_bf16w<<<dim3(C / 128, 8), 256, 0, stream>>>(h2, 1280, Wb2, l1c2b, u, 1280, 500, 512);
        lin10<<<C / 16, 256, 0, stream>>>(u, 512, l2c2w, l2c2b, out2 + (size_t)b0 * 10);

        // stage 3
        conv3_pool<<<C / 4, 256, 0, stream>>>(h2, c3w, c3b, f3);
        lin500<<<C, 256, 0, stream>>>(f3, l1w, l1b, u);
        lin10<<<C / 16, 256, 0, stream>>>(u, 512, l2w, l2b, out3 + (size_t)b0 * 10);
    }

    final_select<<<B_IMG / 256, 256, 0, stream>>>(e1, e2, out1, out2, out3, out);

    (void)in_sizes; (void)n_in; (void)out_size; (void)ws_size;
}